// Round 25
// baseline (44.554 us; speedup 1.0000x reference)
//
#include <hip/hip_runtime.h>
#include <hip/hip_fp16.h>

// Problem constants (B=8, K=32 -> N=256 patches; C=3; H=W=128)
#define HH 128
#define WW 128
#define HW (HH * WW)
#define BAND 16            // output rows per band
#define TROWS 18           // intermediate tile rows (nrows <= 18 proven)

typedef __fp16 h2t __attribute__((ext_vector_type(2)));

__device__ __forceinline__ unsigned int pack2(float x, float y) {
    h2t v = __builtin_amdgcn_cvt_pkrtz(x, y);   // one v_cvt_pkrtz_f16_f32
    unsigned int u;
    __builtin_memcpy(&u, &v, 4);
    return u;
}
__device__ __forceinline__ float f16at(unsigned int u, int odd) {
    unsigned short s = (unsigned short)(u >> (odd ? 16 : 0));
    __half_raw hr; hr.x = s;
    return __half2float(__half(hr));
}

// ---------------------------------------------------------------------------
// Correctness split (R9-R23 verified):
//  - LABELS: index chain BIT-EXACT (CR f32 trig, XLA-FMA rotation, stepwise
//    pix chain, rintf). Values staged f16 (error <=5e-4 << 0.069 threshold).
//  - PATCHES: fast affine f32 coords (verified); VALUES staged f16
//    (adds <=~1e-2 absolute through two convex lerps; threshold 0.069).
// This round: f16 LDS halves footprint -> 37 KB/block -> 4 blocks/CU of
// 512 thr = 32 waves across 4 independent barrier domains (vs 2), halved
// staging bytes, finer tail.
// ---------------------------------------------------------------------------

__device__ __forceinline__ float norm_coord(int i) {
    return __fsub_rn(__fmul_rn((float)(2 * i + 1), 0.0078125f), 1.0f);
}
__device__ __forceinline__ float pix_coord(float g) {
    float t = __fadd_rn(g, 1.0f);
    t = __fmul_rn(t, 128.0f);
    t = __fsub_rn(t, 1.0f);
    return __fmul_rn(t, 0.5f);
}
__device__ __forceinline__ int med127(int v) {
    return min(max(v, 0), 127);     // -> v_med3_i32
}

__global__ void __launch_bounds__(512, 8)
pa_all(const float* __restrict__ patches,
       const float* __restrict__ labels,
       const float* __restrict__ angles,
       const int* __restrict__ flip_h,
       const int* __restrict__ flip_v,
       const float* __restrict__ scales,
       float* __restrict__ out_p,
       float* __restrict__ out_l,
       int nlabel_blocks) {
    __shared__ unsigned int src_h[HW / 2];        // 32 KB f16-packed slice
    __shared__ unsigned int tile_h[TROWS * 64];   // 4.5 KB f16-packed tile
    __shared__ float prm[5];
    int bid = blockIdx.x;
    int tid = threadIdx.x;
    bool is_label = bid < nlabel_blocks;          // labels first
    int n = is_label ? bid : ((bid - nlabel_blocks) / 3);

    if (tid == 0) {
        double a = (double)angles[n];
        prm[0] = (float)cos(a);             // correctly-rounded f32
        prm[1] = (float)sin(a);
        prm[2] = flip_h[n] ? -1.0f : 1.0f;
        prm[3] = flip_v[n] ? -1.0f : 1.0f;
        prm[4] = scales[n];
    }
    __syncthreads();
    float c = prm[0], s = prm[1], fsx = prm[2], fsy = prm[3], sc = prm[4];

    if (!is_label) {
        int slice = bid - nlabel_blocks;    // n*3 + ch

        // ---- stage slice as f16 pairs (float4 -> 2 u32, coalesced) ----
        const float4* g4 = (const float4*)(patches + (size_t)slice * HW);
        #pragma unroll
        for (int i = 0; i < HW / 4 / 512; ++i) {     // 8 iters
            int p = i * 512 + tid;
            float4 v = g4[p];
            src_h[2 * p]     = pack2(v.x, v.y);
            src_h[2 * p + 1] = pack2(v.z, v.w);
        }

        // ---- block-uniform affine: ix = 63.5 + P*(w-63.5) + Q*(h-63.5) ----
        float P = c * fsx, Q = -s * fsy;
        float R = s * fsx, S = c * fsy;

        // ---- lane hoists: 2 adjacent px per thread everywhere ----
        int w2p = (tid & 63) * 2;
        float wm = (float)w2p - 63.5f;
        int rowg = tid >> 6;                // 0..7

        // pass-2 x-side hoists for px (w2p, w2p+1)
        float wx0a, wx1a, wx0b, wx1b;
        int xw0a, xw1a, xw0b, xw1b;         // tile word indices
        int pa0, pa1, pb0, pb1;             // parities
        {
            float ixo = fmaf(sc, wm, 63.5f);
            float xf = floorf(ixo);
            float fx = ixo - xf;
            int xi = (int)xf;
            wx0a = ((unsigned)xi < 128u) ? (1.0f - fx) : 0.0f;
            wx1a = ((unsigned)(xi + 1) < 128u) ? fx : 0.0f;
            int c0 = med127(xi), c1 = med127(xi + 1);
            xw0a = c0 >> 1; pa0 = c0 & 1; xw1a = c1 >> 1; pa1 = c1 & 1;
            float ixo2 = ixo + sc;
            float xf2 = floorf(ixo2);
            float fx2 = ixo2 - xf2;
            int xi2 = (int)xf2;
            wx0b = ((unsigned)xi2 < 128u) ? (1.0f - fx2) : 0.0f;
            wx1b = ((unsigned)(xi2 + 1) < 128u) ? fx2 : 0.0f;
            int d0 = med127(xi2), d1 = med127(xi2 + 1);
            xw0b = d0 >> 1; pb0 = d0 & 1; xw1b = d1 >> 1; pb1 = d1 & 1;
        }
        __syncthreads();

        float* op = out_p + (size_t)slice * HW;

        #pragma unroll
        for (int band = 0; band < HH / BAND; ++band) {       // 8 bands
            int r0 = band * BAND;
            float lof = floorf(fmaf(sc, (float)r0 - 63.5f, 63.5f));
            float hif = floorf(fmaf(sc, (float)(r0 + BAND - 1) - 63.5f, 63.5f)) + 1.0f;
            int lo = max((int)lof, 0);
            int hi = min((int)hif, 127);
            int nrows = hi - lo + 1;                         // <= 18

            // ---- pass 1: rotate+flip from f16 src -> f16 tile, 2px/thr ----
            #pragma unroll
            for (int it = 0; it < 3; ++it) {
                int row = it * 8 + rowg;
                if (row < nrows) {
                    float hf = (float)(lo + row) - 63.5f;
                    float ix = fmaf(P, wm, fmaf(Q, hf, 63.5f));
                    float iy = fmaf(R, wm, fmaf(S, hf, 63.5f));
                    float o01[2];
                    #pragma unroll
                    for (int px = 0; px < 2; ++px) {
                        float xf = floorf(ix), yf = floorf(iy);
                        float fx = ix - xf, fy = iy - yf;
                        int xi = (int)xf, yi = (int)yf;
                        float wx0 = ((unsigned)xi < 128u) ? (1.0f - fx) : 0.0f;
                        float wx1 = ((unsigned)(xi + 1) < 128u) ? fx : 0.0f;
                        float wy0 = ((unsigned)yi < 128u) ? (1.0f - fy) : 0.0f;
                        float wy1 = ((unsigned)(yi + 1) < 128u) ? fy : 0.0f;
                        int c0 = med127(xi), c1 = med127(xi + 1);
                        int y0 = med127(yi) * 64, y1 = med127(yi + 1) * 64;
                        unsigned int a0 = src_h[y0 + (c0 >> 1)];
                        unsigned int a1 = src_h[y0 + (c1 >> 1)];
                        unsigned int b0 = src_h[y1 + (c0 >> 1)];
                        unsigned int b1 = src_h[y1 + (c1 >> 1)];
                        float v00 = f16at(a0, c0 & 1), v10 = f16at(a1, c1 & 1);
                        float v01 = f16at(b0, c0 & 1), v11 = f16at(b1, c1 & 1);
                        float ra = fmaf(wx1, v10, wx0 * v00);
                        float rb = fmaf(wx1, v11, wx0 * v01);
                        o01[px] = fmaf(rb, wy1, ra * wy0);
                        ix += P; iy += R;
                    }
                    tile_h[row * 64 + (tid & 63)] = pack2(o01[0], o01[1]);
                }
            }
            __syncthreads();

            // ---- pass 2: scale from f16 tile, 2 px/thread, float2 out ----
            #pragma unroll
            for (int i = 0; i < 2; ++i) {
                int h = r0 + i * 8 + rowg;
                float iy = fmaf(sc, (float)h - 63.5f, 63.5f);
                float yf = floorf(iy);
                float fy = iy - yf;
                int yi = (int)yf;
                float wy0 = ((unsigned)yi < 128u) ? (1.0f - fy) : 0.0f;
                float wy1 = ((unsigned)(yi + 1) < 128u) ? fy : 0.0f;
                int t0 = (min(max(yi, lo), hi) - lo) * 64;
                int t1 = (min(max(yi + 1, lo), hi) - lo) * 64;
                unsigned int ua00 = tile_h[t0 + xw0a], ua10 = tile_h[t0 + xw1a];
                unsigned int ua01 = tile_h[t1 + xw0a], ua11 = tile_h[t1 + xw1a];
                unsigned int ub00 = tile_h[t0 + xw0b], ub10 = tile_h[t0 + xw1b];
                unsigned int ub01 = tile_h[t1 + xw0b], ub11 = tile_h[t1 + xw1b];
                float ra = fmaf(wx1a, f16at(ua10, pa1), wx0a * f16at(ua00, pa0));
                float rb = fmaf(wx1a, f16at(ua11, pa1), wx0a * f16at(ua01, pa0));
                float ox = fmaf(rb, wy1, ra * wy0);
                float rc = fmaf(wx1b, f16at(ub10, pb1), wx0b * f16at(ub00, pb0));
                float rd = fmaf(wx1b, f16at(ub11, pb1), wx0b * f16at(ub01, pb0));
                float oy = fmaf(rd, wy1, rc * wy0);
                float2 o2;
                o2.x = ox;
                o2.y = oy;
                *(float2*)&op[h * WW + w2p] = o2;
            }
            __syncthreads();   // tile reused by next band
        }
    } else {
        // ----- label path: BIT-EXACT index chain, f16-staged values -----
        const float4* g4 = (const float4*)(labels + (size_t)n * HW);
        #pragma unroll
        for (int i = 0; i < HW / 4 / 512; ++i) {
            int p = i * 512 + tid;
            float4 v = g4[p];
            src_h[2 * p]     = pack2(v.x, v.y);
            src_h[2 * p + 1] = pack2(v.z, v.w);
        }
        __syncthreads();

        float* ol = out_l + (size_t)n * HW;
        int w = tid & (WW - 1);

        float ix2 = pix_coord(__fmul_rn(sc, norm_coord(w)));
        float xr2 = rintf(ix2);
        bool okx2 = (xr2 >= 0.0f) && (xr2 <= 127.0f);
        int w2 = (int)xr2;
        float xw2 = okx2 ? __fmul_rn(fsx, norm_coord(w2)) : 0.0f;
        float cx = __fmul_rn(c, xw2);
        float sx = __fmul_rn(s, xw2);

        #pragma unroll 4
        for (int i = 0; i < HW / 512; ++i) {         // 32 iters
            int p = i * 512 + tid;
            int h = p >> 7;
            float iy2 = pix_coord(__fmul_rn(sc, norm_coord(h)));
            float yr2 = rintf(iy2);
            float outv = 0.0f;
            if (okx2 && yr2 >= 0.0f && yr2 <= 127.0f) {
                int h2 = (int)yr2;
                float y = __fmul_rn(fsy, norm_coord(h2));
                float xr1 = rintf(pix_coord(__fmaf_rn(-s, y, cx)));
                float yr1 = rintf(pix_coord(__fmaf_rn(c, y, sx)));
                if (xr1 >= 0.0f && xr1 <= 127.0f &&
                    yr1 >= 0.0f && yr1 <= 127.0f) {
                    int idx = (int)yr1 * WW + (int)xr1;
                    outv = f16at(src_h[idx >> 1], idx & 1);
                }
            }
            ol[p] = outv;
        }
    }
}

extern "C" void kernel_launch(void* const* d_in, const int* in_sizes, int n_in,
                              void* d_out, int out_size, void* d_ws, size_t ws_size,
                              hipStream_t stream) {
    const float* patches = (const float*)d_in[0];
    const float* labels  = (const float*)d_in[1];
    const float* angles  = (const float*)d_in[2];
    const int*   flip_h  = (const int*)d_in[3];
    const int*   flip_v  = (const int*)d_in[4];
    const float* scales  = (const float*)d_in[5];

    const int N = in_sizes[2];            // B*K = 256
    float* out   = (float*)d_out;
    float* out_p = out;                   // N*3*H*W
    float* out_l = out + (size_t)N * 3 * HW;

    int nlabel_blocks = N;                // 256 label blocks first
    int npatch_blocks = N * 3;            // 768 patch-slice blocks
    pa_all<<<nlabel_blocks + npatch_blocks, 512, 0, stream>>>(
        patches, labels, angles, flip_h, flip_v, scales,
        out_p, out_l, nlabel_blocks);
}

// Round 26
// 37.919 us; speedup vs baseline: 1.1750x; 1.1750x over previous
//
#include <hip/hip_runtime.h>

// Problem constants (B=8, K=32 -> N=256 patches; C=3; H=W=128)
#define HH 128
#define WW 128
#define HW (HH * WW)
#define BAND 16            // output rows per band
#define TROWS 18           // intermediate tile rows (nrows <= 18 proven)

typedef float v2f __attribute__((ext_vector_type(2)));   // NT-store-compatible

// ---------------------------------------------------------------------------
// FINAL-FAMILY KERNEL: exact R18 structure (empirical best, 40.3 us) + NT
// output stores (outputs never re-read; preserve L2/L3 for src).
// Correctness split (R9-R25 verified):
//  - LABELS (nearest): bit-exact chain (CR f32 trig, XLA-FMA rotation,
//    stepwise pix chain, rintf half-even, OOB->0).
//  - PATCHES (bilinear): continuous in coords; fast affine forms verified
//    (absmax 0.008 vs threshold 0.069).
// Structure: full 64 KB slice in LDS (1x fetch, conflict-free b128 staging),
// 8 banded pass-1/pass-2 rounds; adjacent-pair tap loads (ds_read2_b32);
// 2 px/thread with float2 tile writes.
// Pair trick: load (xb, xb+1) with xb=med127(xi); v1=(xi>=0)?pb:pa.
//   xi=-1: v1=pa=px0 (correct; v0 weight-masked). xi=127: pb spills into
//   tile[] (defined LDS, weight-masked 0). xi in [0,126]: exact taps.
// ---------------------------------------------------------------------------

__device__ __forceinline__ float norm_coord(int i) {
    return __fsub_rn(__fmul_rn((float)(2 * i + 1), 0.0078125f), 1.0f);
}

__device__ __forceinline__ float pix_coord(float g) {
    float t = __fadd_rn(g, 1.0f);
    t = __fmul_rn(t, 128.0f);
    t = __fsub_rn(t, 1.0f);
    return __fmul_rn(t, 0.5f);
}

__device__ __forceinline__ int med127(int v) {
    return min(max(v, 0), 127);     // -> v_med3_i32
}

__global__ void __launch_bounds__(1024, 8)
pa_all(const float* __restrict__ patches,
       const float* __restrict__ labels,
       const float* __restrict__ angles,
       const int* __restrict__ flip_h,
       const int* __restrict__ flip_v,
       const float* __restrict__ scales,
       float* __restrict__ out_p,
       float* __restrict__ out_l,
       int npatch_blocks) {
    __shared__ float src[HW];               // 64 KB full source slice
    __shared__ float tile[TROWS * WW];      // 9 KB pass-1 intermediate band
    __shared__ float prm[5];
    int bid = blockIdx.x;
    int tid = threadIdx.x;
    bool is_patch = bid < npatch_blocks;
    int n = is_patch ? (bid / 3) : (bid - npatch_blocks);

    if (tid == 0) {
        double a = (double)angles[n];
        prm[0] = (float)cos(a);             // correctly-rounded f32
        prm[1] = (float)sin(a);
        prm[2] = flip_h[n] ? -1.0f : 1.0f;
        prm[3] = flip_v[n] ? -1.0f : 1.0f;
        prm[4] = scales[n];
    }
    __syncthreads();
    float c = prm[0], s = prm[1], fsx = prm[2], fsy = prm[3], sc = prm[4];

    if (is_patch) {
        int slice = bid;                    // n*3 + ch

        // ---- stage full slice coalesced (float4, exactly 1x fetch) ----
        const float4* g4 = (const float4*)(patches + (size_t)slice * HW);
        float4* s4 = (float4*)src;
        #pragma unroll
        for (int i = 0; i < HW / 4 / 1024; ++i)      // 4 iters
            s4[i * 1024 + tid] = g4[i * 1024 + tid];

        // ---- per-lane hoists (fast affine coords; patches only) ----
        int w2 = (tid & 63) * 2;            // 2 adjacent px per thread
        float nx = fmaf((float)(2 * w2 + 1), 0.0078125f, -1.0f);
        float xw = fsx * nx;
        float cx = c * xw, sxw = s * xw;
        float sfsy = s * fsy, cfsy = c * fsy;
        float Cx = c * fsx;                 // d(ix)/dw
        float Sx = s * fsx;                 // d(iy)/dw
        // pass-1 affine: ix = Ax + Bx*h (for px w2), ix(w2+1) = ix + Cx
        float Ax = fmaf(sfsy, 63.5f, fmaf(64.0f, cx, 63.5f));
        float Bx = -sfsy;
        float Ay = fmaf(cfsy, -63.5f, fmaf(64.0f, sxw, 63.5f));
        float By = cfsy;
        // pass-2 y affine: iy = sc*h + Cy
        float Cy = fmaf(-63.5f, sc, 63.5f);

        // pass-2 x-side hoists for px (w2, w2+1): pair bases + weights
        float wx0a, wx1a, wx0b, wx1b;
        int xba, xbb;
        bool pxa, pxb;                      // xi >= 0 (pair-select bits)
        {
            float ixo = fmaf(64.0f * sc, nx, 63.5f);
            float x0f = floorf(ixo);
            float fx = ixo - x0f;
            int xi = (int)x0f;
            wx0a = ((unsigned)xi < 128u) ? (1.0f - fx) : 0.0f;
            wx1a = ((unsigned)(xi + 1) < 128u) ? fx : 0.0f;
            xba = med127(xi); pxa = xi >= 0;
            float ixo2 = ixo + sc;          // next px: +d(ix)/dw = sc
            float x0f2 = floorf(ixo2);
            float fx2 = ixo2 - x0f2;
            int xi2 = (int)x0f2;
            wx0b = ((unsigned)xi2 < 128u) ? (1.0f - fx2) : 0.0f;
            wx1b = ((unsigned)(xi2 + 1) < 128u) ? fx2 : 0.0f;
            xbb = med127(xi2); pxb = xi2 >= 0;
        }
        int prow = tid >> 6;                // pass-2 row 0..15 within band
        __syncthreads();

        float* op = out_p + (size_t)slice * HW;

        #pragma unroll
        for (int band = 0; band < HH / BAND; ++band) {       // 8 bands
            int r0 = band * BAND;
            int lo = max((int)floorf(fmaf(sc, (float)r0, Cy)), 0);
            int hi = min((int)floorf(fmaf(sc, (float)(r0 + BAND - 1), Cy)) + 1, 127);
            int nrows = hi - lo + 1;                         // <= 18

            // ---- pass 1: rotate+flip from LDS src -> tile (2 px/thread) ----
            #pragma unroll
            for (int it = 0; it < 2; ++it) {                 // 16 rows, then 2
                int row = it * 16 + (tid >> 6);
                if (row < nrows) {
                    float hf = (float)(lo + row);
                    float o01[2];
                    float ix = fmaf(Bx, hf, Ax);
                    float iy = fmaf(By, hf, Ay);
                    #pragma unroll
                    for (int px = 0; px < 2; ++px) {
                        float x0f = floorf(ix), y0f = floorf(iy);
                        float fx = ix - x0f, fy = iy - y0f;
                        int xi = (int)x0f, yi = (int)y0f;
                        float wx0 = ((unsigned)xi < 128u) ? (1.0f - fx) : 0.0f;
                        float wx1 = ((unsigned)(xi + 1) < 128u) ? fx : 0.0f;
                        float wy0 = ((unsigned)yi < 128u) ? (1.0f - fy) : 0.0f;
                        float wy1 = ((unsigned)(yi + 1) < 128u) ? fy : 0.0f;
                        int xb = med127(xi);
                        bool ps = xi >= 0;
                        const float* r0p = &src[med127(yi) * WW + xb];
                        const float* r1p = &src[med127(yi + 1) * WW + xb];
                        float p0a = r0p[0], p0b = r0p[1];    // ds_read2_b32
                        float p1a = r1p[0], p1b = r1p[1];    // ds_read2_b32
                        float v10 = ps ? p0b : p0a;
                        float v11 = ps ? p1b : p1a;
                        float ra = fmaf(wx1, v10, wx0 * p0a);
                        float rb = fmaf(wx1, v11, wx0 * p1a);
                        o01[px] = fmaf(rb, wy1, ra * wy0);
                        ix += Cx; iy += Sx;
                    }
                    *(float2*)&tile[row * WW + w2] = make_float2(o01[0], o01[1]);
                }
            }
            __syncthreads();

            // ---- pass 2: scale from tile, 2 px/thread, NT float2 store ----
            {
                int h = r0 + prow;
                float iy = fmaf(sc, (float)h, Cy);
                float y0f = floorf(iy);
                float fy = iy - y0f;
                int yi = (int)y0f;
                float wy0 = ((unsigned)yi < 128u) ? (1.0f - fy) : 0.0f;
                float wy1 = ((unsigned)(yi + 1) < 128u) ? fy : 0.0f;
                int t0 = (min(max(yi, lo), hi) - lo) * WW;
                int t1 = (min(max(yi + 1, lo), hi) - lo) * WW;
                const float* ta0 = &tile[t0 + xba];
                const float* ta1 = &tile[t1 + xba];
                const float* tb0 = &tile[t0 + xbb];
                const float* tb1 = &tile[t1 + xbb];
                float a0a = ta0[0], a0b = ta0[1];            // ds_read2_b32
                float a1a = ta1[0], a1b = ta1[1];
                float b0a = tb0[0], b0b = tb0[1];
                float b1a = tb1[0], b1b = tb1[1];
                float v10a = pxa ? a0b : a0a;
                float v11a = pxa ? a1b : a1a;
                float v10b = pxb ? b0b : b0a;
                float v11b = pxb ? b1b : b1a;
                float raa = fmaf(wx1a, v10a, wx0a * a0a);
                float rba = fmaf(wx1a, v11a, wx0a * a1a);
                float rab = fmaf(wx1b, v10b, wx0b * b0a);
                float rbb = fmaf(wx1b, v11b, wx0b * b1a);
                v2f o2;
                o2.x = fmaf(rba, wy1, raa * wy0);
                o2.y = fmaf(rbb, wy1, rab * wy0);
                __builtin_nontemporal_store(o2, (v2f*)&op[h * WW + w2]);
            }
            __syncthreads();   // tile reused by next band
        }
    } else {
        // ----- label path: BIT-EXACT fused nearest-of-nearest (R9 chain) -----
        const float* lab = labels + (size_t)n * HW;
        float* ol = out_l + (size_t)n * HW;
        int w = tid & (WW - 1);

        float ix2 = pix_coord(__fmul_rn(sc, norm_coord(w)));
        float xr2 = rintf(ix2);
        bool okx2 = (xr2 >= 0.0f) && (xr2 <= 127.0f);
        int w2 = (int)xr2;
        float xw2 = okx2 ? __fmul_rn(fsx, norm_coord(w2)) : 0.0f;
        float cx = __fmul_rn(c, xw2);
        float sx = __fmul_rn(s, xw2);

        #pragma unroll 4
        for (int i = 0; i < HW / 1024; ++i) {        // 16 iters
            int p = i * 1024 + tid;
            int h = p >> 7;
            float iy2 = pix_coord(__fmul_rn(sc, norm_coord(h)));
            float yr2 = rintf(iy2);
            float outv = 0.0f;
            if (okx2 && yr2 >= 0.0f && yr2 <= 127.0f) {
                int h2 = (int)yr2;
                float y = __fmul_rn(fsy, norm_coord(h2));
                float xr1 = rintf(pix_coord(__fmaf_rn(-s, y, cx)));
                float yr1 = rintf(pix_coord(__fmaf_rn(c, y, sx)));
                if (xr1 >= 0.0f && xr1 <= 127.0f &&
                    yr1 >= 0.0f && yr1 <= 127.0f) {
                    outv = lab[(int)yr1 * WW + (int)xr1];
                }
            }
            __builtin_nontemporal_store(outv, &ol[p]);
        }
    }
}

extern "C" void kernel_launch(void* const* d_in, const int* in_sizes, int n_in,
                              void* d_out, int out_size, void* d_ws, size_t ws_size,
                              hipStream_t stream) {
    const float* patches = (const float*)d_in[0];
    const float* labels  = (const float*)d_in[1];
    const float* angles  = (const float*)d_in[2];
    const int*   flip_h  = (const int*)d_in[3];
    const int*   flip_v  = (const int*)d_in[4];
    const float* scales  = (const float*)d_in[5];

    const int N = in_sizes[2];            // B*K = 256
    float* out   = (float*)d_out;
    float* out_p = out;                   // N*3*H*W
    float* out_l = out + (size_t)N * 3 * HW;

    int npatch_blocks = N * 3;            // 768: one per channel slice
    int nlabel_blocks = N;                // 256: one per label slice
    pa_all<<<npatch_blocks + nlabel_blocks, 1024, 0, stream>>>(
        patches, labels, angles, flip_h, flip_v, scales,
        out_p, out_l, npatch_blocks);
}

// Round 27
// 37.853 us; speedup vs baseline: 1.1770x; 1.0017x over previous
//
#include <hip/hip_runtime.h>

// Problem constants (B=8, K=32 -> N=256 patches; C=3; H=W=128)
#define HH 128
#define WW 128
#define HW (HH * WW)
#define BAND 16            // output rows per band
#define TROWS 18           // intermediate tile rows (nrows <= 18 proven)

typedef float v2f __attribute__((ext_vector_type(2)));   // NT-compatible
typedef float v4f __attribute__((ext_vector_type(4)));   // NT-compatible

// ---------------------------------------------------------------------------
// FINAL-FAMILY KERNEL: R26 (37.9 us) + nontemporal STAGING LOADS.
// All source slices are single-touch streams (staged to LDS once); NT-hint
// them so L2/L3 stay free for the label gathers (the only reuse traffic).
// Correctness split (R9-R26 verified):
//  - LABELS (nearest): bit-exact chain (CR f32 trig, XLA-FMA rotation,
//    stepwise pix chain, rintf half-even, OOB->0). Gather loads normal
//    (intra-block line reuse).
//  - PATCHES (bilinear): fast affine f32 coords (verified, absmax 0.008
//    vs threshold 0.069).
// Structure: full 64 KB slice in LDS (1x fetch), 8 banded pass-1/pass-2
// rounds; adjacent-pair tap loads (ds_read2_b32); 2 px/thread; NT stores.
// ---------------------------------------------------------------------------

__device__ __forceinline__ float norm_coord(int i) {
    return __fsub_rn(__fmul_rn((float)(2 * i + 1), 0.0078125f), 1.0f);
}

__device__ __forceinline__ float pix_coord(float g) {
    float t = __fadd_rn(g, 1.0f);
    t = __fmul_rn(t, 128.0f);
    t = __fsub_rn(t, 1.0f);
    return __fmul_rn(t, 0.5f);
}

__device__ __forceinline__ int med127(int v) {
    return min(max(v, 0), 127);     // -> v_med3_i32
}

__global__ void __launch_bounds__(1024, 8)
pa_all(const float* __restrict__ patches,
       const float* __restrict__ labels,
       const float* __restrict__ angles,
       const int* __restrict__ flip_h,
       const int* __restrict__ flip_v,
       const float* __restrict__ scales,
       float* __restrict__ out_p,
       float* __restrict__ out_l,
       int npatch_blocks) {
    __shared__ float src[HW];               // 64 KB full source slice
    __shared__ float tile[TROWS * WW];      // 9 KB pass-1 intermediate band
    __shared__ float prm[5];
    int bid = blockIdx.x;
    int tid = threadIdx.x;
    bool is_patch = bid < npatch_blocks;
    int n = is_patch ? (bid / 3) : (bid - npatch_blocks);

    if (tid == 0) {
        double a = (double)angles[n];
        prm[0] = (float)cos(a);             // correctly-rounded f32
        prm[1] = (float)sin(a);
        prm[2] = flip_h[n] ? -1.0f : 1.0f;
        prm[3] = flip_v[n] ? -1.0f : 1.0f;
        prm[4] = scales[n];
    }
    __syncthreads();
    float c = prm[0], s = prm[1], fsx = prm[2], fsy = prm[3], sc = prm[4];

    if (is_patch) {
        int slice = bid;                    // n*3 + ch

        // ---- stage full slice coalesced (NT v4f loads, exactly 1x fetch) ----
        const v4f* g4 = (const v4f*)(patches + (size_t)slice * HW);
        v4f* s4 = (v4f*)src;
        #pragma unroll
        for (int i = 0; i < HW / 4 / 1024; ++i)      // 4 iters
            s4[i * 1024 + tid] = __builtin_nontemporal_load(&g4[i * 1024 + tid]);

        // ---- per-lane hoists (fast affine coords; patches only) ----
        int w2 = (tid & 63) * 2;            // 2 adjacent px per thread
        float nx = fmaf((float)(2 * w2 + 1), 0.0078125f, -1.0f);
        float xw = fsx * nx;
        float cx = c * xw, sxw = s * xw;
        float sfsy = s * fsy, cfsy = c * fsy;
        float Cx = c * fsx;                 // d(ix)/dw
        float Sx = s * fsx;                 // d(iy)/dw
        // pass-1 affine: ix = Ax + Bx*h (for px w2), ix(w2+1) = ix + Cx
        float Ax = fmaf(sfsy, 63.5f, fmaf(64.0f, cx, 63.5f));
        float Bx = -sfsy;
        float Ay = fmaf(cfsy, -63.5f, fmaf(64.0f, sxw, 63.5f));
        float By = cfsy;
        // pass-2 y affine: iy = sc*h + Cy
        float Cy = fmaf(-63.5f, sc, 63.5f);

        // pass-2 x-side hoists for px (w2, w2+1): pair bases + weights
        float wx0a, wx1a, wx0b, wx1b;
        int xba, xbb;
        bool pxa, pxb;                      // xi >= 0 (pair-select bits)
        {
            float ixo = fmaf(64.0f * sc, nx, 63.5f);
            float x0f = floorf(ixo);
            float fx = ixo - x0f;
            int xi = (int)x0f;
            wx0a = ((unsigned)xi < 128u) ? (1.0f - fx) : 0.0f;
            wx1a = ((unsigned)(xi + 1) < 128u) ? fx : 0.0f;
            xba = med127(xi); pxa = xi >= 0;
            float ixo2 = ixo + sc;          // next px: +d(ix)/dw = sc
            float x0f2 = floorf(ixo2);
            float fx2 = ixo2 - x0f2;
            int xi2 = (int)x0f2;
            wx0b = ((unsigned)xi2 < 128u) ? (1.0f - fx2) : 0.0f;
            wx1b = ((unsigned)(xi2 + 1) < 128u) ? fx2 : 0.0f;
            xbb = med127(xi2); pxb = xi2 >= 0;
        }
        int prow = tid >> 6;                // pass-2 row 0..15 within band
        __syncthreads();

        float* op = out_p + (size_t)slice * HW;

        #pragma unroll
        for (int band = 0; band < HH / BAND; ++band) {       // 8 bands
            int r0 = band * BAND;
            int lo = max((int)floorf(fmaf(sc, (float)r0, Cy)), 0);
            int hi = min((int)floorf(fmaf(sc, (float)(r0 + BAND - 1), Cy)) + 1, 127);
            int nrows = hi - lo + 1;                         // <= 18

            // ---- pass 1: rotate+flip from LDS src -> tile (2 px/thread) ----
            #pragma unroll
            for (int it = 0; it < 2; ++it) {                 // 16 rows, then 2
                int row = it * 16 + (tid >> 6);
                if (row < nrows) {
                    float hf = (float)(lo + row);
                    float o01[2];
                    float ix = fmaf(Bx, hf, Ax);
                    float iy = fmaf(By, hf, Ay);
                    #pragma unroll
                    for (int px = 0; px < 2; ++px) {
                        float x0f = floorf(ix), y0f = floorf(iy);
                        float fx = ix - x0f, fy = iy - y0f;
                        int xi = (int)x0f, yi = (int)y0f;
                        float wx0 = ((unsigned)xi < 128u) ? (1.0f - fx) : 0.0f;
                        float wx1 = ((unsigned)(xi + 1) < 128u) ? fx : 0.0f;
                        float wy0 = ((unsigned)yi < 128u) ? (1.0f - fy) : 0.0f;
                        float wy1 = ((unsigned)(yi + 1) < 128u) ? fy : 0.0f;
                        int xb = med127(xi);
                        bool ps = xi >= 0;
                        const float* r0p = &src[med127(yi) * WW + xb];
                        const float* r1p = &src[med127(yi + 1) * WW + xb];
                        float p0a = r0p[0], p0b = r0p[1];    // ds_read2_b32
                        float p1a = r1p[0], p1b = r1p[1];    // ds_read2_b32
                        float v10 = ps ? p0b : p0a;
                        float v11 = ps ? p1b : p1a;
                        float ra = fmaf(wx1, v10, wx0 * p0a);
                        float rb = fmaf(wx1, v11, wx0 * p1a);
                        o01[px] = fmaf(rb, wy1, ra * wy0);
                        ix += Cx; iy += Sx;
                    }
                    *(float2*)&tile[row * WW + w2] = make_float2(o01[0], o01[1]);
                }
            }
            __syncthreads();

            // ---- pass 2: scale from tile, 2 px/thread, NT float2 store ----
            {
                int h = r0 + prow;
                float iy = fmaf(sc, (float)h, Cy);
                float y0f = floorf(iy);
                float fy = iy - y0f;
                int yi = (int)y0f;
                float wy0 = ((unsigned)yi < 128u) ? (1.0f - fy) : 0.0f;
                float wy1 = ((unsigned)(yi + 1) < 128u) ? fy : 0.0f;
                int t0 = (min(max(yi, lo), hi) - lo) * WW;
                int t1 = (min(max(yi + 1, lo), hi) - lo) * WW;
                const float* ta0 = &tile[t0 + xba];
                const float* ta1 = &tile[t1 + xba];
                const float* tb0 = &tile[t0 + xbb];
                const float* tb1 = &tile[t1 + xbb];
                float a0a = ta0[0], a0b = ta0[1];            // ds_read2_b32
                float a1a = ta1[0], a1b = ta1[1];
                float b0a = tb0[0], b0b = tb0[1];
                float b1a = tb1[0], b1b = tb1[1];
                float v10a = pxa ? a0b : a0a;
                float v11a = pxa ? a1b : a1a;
                float v10b = pxb ? b0b : b0a;
                float v11b = pxb ? b1b : b1a;
                float raa = fmaf(wx1a, v10a, wx0a * a0a);
                float rba = fmaf(wx1a, v11a, wx0a * a1a);
                float rab = fmaf(wx1b, v10b, wx0b * b0a);
                float rbb = fmaf(wx1b, v11b, wx0b * b1a);
                v2f o2;
                o2.x = fmaf(rba, wy1, raa * wy0);
                o2.y = fmaf(rbb, wy1, rab * wy0);
                __builtin_nontemporal_store(o2, (v2f*)&op[h * WW + w2]);
            }
            __syncthreads();   // tile reused by next band
        }
    } else {
        // ----- label path: BIT-EXACT fused nearest-of-nearest (R9 chain) -----
        const float* lab = labels + (size_t)n * HW;
        float* ol = out_l + (size_t)n * HW;
        int w = tid & (WW - 1);

        float ix2 = pix_coord(__fmul_rn(sc, norm_coord(w)));
        float xr2 = rintf(ix2);
        bool okx2 = (xr2 >= 0.0f) && (xr2 <= 127.0f);
        int w2 = (int)xr2;
        float xw2 = okx2 ? __fmul_rn(fsx, norm_coord(w2)) : 0.0f;
        float cx = __fmul_rn(c, xw2);
        float sx = __fmul_rn(s, xw2);

        #pragma unroll 4
        for (int i = 0; i < HW / 1024; ++i) {        // 16 iters
            int p = i * 1024 + tid;
            int h = p >> 7;
            float iy2 = pix_coord(__fmul_rn(sc, norm_coord(h)));
            float yr2 = rintf(iy2);
            float outv = 0.0f;
            if (okx2 && yr2 >= 0.0f && yr2 <= 127.0f) {
                int h2 = (int)yr2;
                float y = __fmul_rn(fsy, norm_coord(h2));
                float xr1 = rintf(pix_coord(__fmaf_rn(-s, y, cx)));
                float yr1 = rintf(pix_coord(__fmaf_rn(c, y, sx)));
                if (xr1 >= 0.0f && xr1 <= 127.0f &&
                    yr1 >= 0.0f && yr1 <= 127.0f) {
                    outv = lab[(int)yr1 * WW + (int)xr1];   // normal load: reuse
                }
            }
            __builtin_nontemporal_store(outv, &ol[p]);
        }
    }
}

extern "C" void kernel_launch(void* const* d_in, const int* in_sizes, int n_in,
                              void* d_out, int out_size, void* d_ws, size_t ws_size,
                              hipStream_t stream) {
    const float* patches = (const float*)d_in[0];
    const float* labels  = (const float*)d_in[1];
    const float* angles  = (const float*)d_in[2];
    const int*   flip_h  = (const int*)d_in[3];
    const int*   flip_v  = (const int*)d_in[4];
    const float* scales  = (const float*)d_in[5];

    const int N = in_sizes[2];            // B*K = 256
    float* out   = (float*)d_out;
    float* out_p = out;                   // N*3*H*W
    float* out_l = out + (size_t)N * 3 * HW;

    int npatch_blocks = N * 3;            // 768: one per channel slice
    int nlabel_blocks = N;                // 256: one per label slice
    pa_all<<<npatch_blocks + nlabel_blocks, 1024, 0, stream>>>(
        patches, labels, angles, flip_h, flip_v, scales,
        out_p, out_l, npatch_blocks);
}